// Round 7
// baseline (76.056 us; speedup 1.0000x reference)
//
#include <hip/hip_runtime.h>
#include <stdint.h>

#define NBOX 6400
#define GRIDW 80
#define NC 20
#define NBLK 100      // NBOX / 64
#define MAGIC 0x13579BDFu

__device__ __forceinline__ float sigmoidf(float x) { return 1.0f / (1.0f + expf(-x)); }

// Full per-box decode, exact reference formulas (outputs must be bit-faithful).
__device__ __forceinline__ void decode_one(const float* __restrict__ p, int n,
        float4* box, float* score, int* cls) {
    float conf = sigmoidf(p[0]);
    float c[NC];
    float m = -INFINITY;
    #pragma unroll
    for (int j = 0; j < NC; j++) { c[j] = p[1 + j]; m = fmaxf(m, c[j]); }
    float sum = 0.f;
    #pragma unroll
    for (int j = 0; j < NC; j++) { c[j] = expf(c[j] - m); sum += c[j]; }
    float best = -INFINITY; int bi = 0;
    #pragma unroll
    for (int j = 0; j < NC; j++) {
        float s = (c[j] / sum) * conf;        // softmax*conf, first-max argmax
        if (s > best) { best = s; bi = j; }
    }
    float gx = (float)(n / GRIDW);            // meshgrid 'ij': n = gx*80 + gy
    float gy = (float)(n % GRIDW);
    float cx = (gx + sigmoidf(p[21])) * 32.0f;
    float cy = (gy + sigmoidf(p[22])) * 32.0f;
    float w = expf(p[23]);
    float h = expf(p[24]);
    box->x = fminf(fmaxf((cx - w * 0.5f) / 2560.0f, 0.0f), 1.0f);
    box->y = fminf(fmaxf((cy - h * 0.5f) / 2560.0f, 0.0f), 1.0f);
    box->z = fminf(fmaxf((cx + w * 0.5f) / 2560.0f, 0.0f), 1.0f);
    box->w = fminf(fmaxf((cy + h * 0.5f) / 2560.0f, 0.0f), 1.0f);
    *score = best;
    *cls = bi;
}

// Single dispatch, 100 blocks x 256 (<=1 block/CU on 256 CUs -> co-resident).
// Phase 1: wave 0 decodes own 64-box chunk, writes outputs + chunk bbox/ballot.
// Grid barrier: init-free per-block MAGIC ready flags (device-scope atomics;
// works for ANY prior ws contents — no counter-base assumption, no init race).
// Phase 2: bbox screen + LDS-staged conservative IoU>0.5 pair test (as R6).
// Fallback: block 0 waits on ready2, runs exact NMS iff flag==1 (never here).
__global__ __launch_bounds__(256) void k_all(const float* __restrict__ pred,
        float* __restrict__ out, float4* __restrict__ boff,
        float* __restrict__ score, float4* __restrict__ blkbb,
        uint64_t* __restrict__ validw, uint32_t* __restrict__ flag,
        uint32_t* __restrict__ ready, uint32_t* __restrict__ ready2,
        int* __restrict__ sidx, float* __restrict__ sscore,
        float4* __restrict__ sbox) {
    __shared__ float4 rowbox[64];          // own chunk's offset boxes
    __shared__ float4 cblds[64];           // staged column boxes
    __shared__ uint64_t sh_rowvalid;
    __shared__ float4 sh_ra;
    __shared__ uint32_t sh_flag;
    __shared__ uint64_t klds[NBOX];        // 51.2 KB, fallback only
    __shared__ uint32_t keepb[NBOX / 32];  // fallback only
    int t = threadIdx.x;
    int w = t >> 6, l = t & 63;
    int bi = blockIdx.x;

    // ---- phase 1: decode own chunk (wave 0) ----
    if (t < 64) {
        int n = bi * 64 + t;
        float4 bx; float s; int cls;
        decode_one(pred + (size_t)n * 25, n, &bx, &s, &cls);
        ((float4*)out)[n] = bx;               // output 0: boxes
        out[32000 + n] = (float)cls;          // output 2: class_idx
        bool valid = s >= 0.01f;
        out[25600 + n] = valid ? s : 0.0f;    // output 1: scores*keep (fast path)
        out[38400 + n] = valid ? 1.0f : 0.0f; // output 3: keep (fast path)
        score[n] = s;
        float off = 2.0f * (float)cls;        // class-offset trick
        float4 ob = make_float4(bx.x + off, bx.y + off, bx.z + off, bx.w + off);
        boff[n] = ob;
        rowbox[t] = ob;
        // chunk bbox over valid boxes (un-offset geometry; conservative screen)
        float x1 = valid ? bx.x :  INFINITY;
        float y1 = valid ? bx.y :  INFINITY;
        float x2 = valid ? bx.z : -INFINITY;
        float y2 = valid ? bx.w : -INFINITY;
        #pragma unroll
        for (int d = 1; d < 64; d <<= 1) {
            x1 = fminf(x1, __shfl_xor(x1, d));
            y1 = fminf(y1, __shfl_xor(y1, d));
            x2 = fmaxf(x2, __shfl_xor(x2, d));
            y2 = fmaxf(y2, __shfl_xor(y2, d));
        }
        uint64_t vb = __ballot(valid);
        if (t == 0) {
            float4 ra = make_float4(x1, y1, x2, y2);
            blkbb[bi] = ra;
            validw[bi] = vb;
            sh_rowvalid = vb;
            sh_ra = ra;
        }
    }
    __syncthreads();
    if (t == 0) {
        __threadfence();   // publish chunk data (device scope)
        __hip_atomic_store(&ready[bi], MAGIC, __ATOMIC_RELEASE, __HIP_MEMORY_SCOPE_AGENT);
    }
    // ---- grid barrier: wave 0 spins until all 100 ready flags == MAGIC ----
    if (t < 64) {
        bool need0 = (t < NBLK), need1 = (t + 64 < NBLK);
        for (;;) {
            bool ok = (!need0 || __hip_atomic_load(&ready[t], __ATOMIC_RELAXED,
                                     __HIP_MEMORY_SCOPE_AGENT) == MAGIC)
                   && (!need1 || __hip_atomic_load(&ready[t + 64], __ATOMIC_RELAXED,
                                     __HIP_MEMORY_SCOPE_AGENT) == MAGIC);
            if (__ballot(ok) == ~0ull) break;
            __builtin_amdgcn_s_sleep(8);
        }
    }
    __syncthreads();
    __threadfence();       // acquire: remote chunk data now safe to read

    // ---- phase 2: screen + fine pair test (identical ballots in all waves) ----
    float4 ra = sh_ra;
    uint64_t rowvalid = sh_rowvalid;
    const float M = 1e-5f;
    uint64_t surv_lo = 0ull, surv_hi = 0ull;
    if (rowvalid != 0ull) {
        bool ov = false;
        int bj = bi + l;
        if (bj < NBLK) {
            float4 ca = blkbb[bj];
            ov = (fminf(ra.z, ca.z) + M >= fmaxf(ra.x, ca.x)) &&
                 (fminf(ra.w, ca.w) + M >= fmaxf(ra.y, ca.y));
        }
        surv_lo = __ballot(ov);
        ov = false;
        bj = bi + 64 + l;
        if (bj < NBLK) {
            float4 ca = blkbb[bj];
            ov = (fminf(ra.z, ca.z) + M >= fmaxf(ra.x, ca.x)) &&
                 (fminf(ra.w, ca.w) + M >= fmaxf(ra.y, ca.y));
        }
        surv_hi = __ballot(ov);
    }
    float4 rb = rowbox[l];                // each wave covers all 64 rows
    float areai = (rb.z - rb.x) * (rb.w - rb.y);
    bool rv = (rowvalid >> l) & 1ull;
    bool hit = false;
    while ((surv_lo | surv_hi) != 0ull) { // uniform across block
        int d;
        if (surv_lo) { d = __ffsll((unsigned long long)surv_lo) - 1; surv_lo &= surv_lo - 1; }
        else { d = 64 + __ffsll((unsigned long long)surv_hi) - 1; surv_hi &= surv_hi - 1; }
        int bj = bi + d;
        uint64_t colvalid = validw[bj];
        __syncthreads();
        if (t < 64) cblds[t] = boff[bj * 64 + t];
        __syncthreads();
        if (colvalid != 0ull) {
            #pragma unroll
            for (int k2 = 0; k2 < 16; k2++) {
                int s2 = w * 16 + k2;                 // wave-uniform column
                float4 b = cblds[s2];                 // LDS broadcast read
                bool ok = rv && ((colvalid >> s2) & 1ull) &&
                          !(bi == bj && s2 <= l);     // unordered pairs once
                float xx1 = fmaxf(rb.x, b.x);
                float yy1 = fmaxf(rb.y, b.y);
                float xx2 = fminf(rb.z, b.z);
                float yy2 = fminf(rb.w, b.w);
                float ww = fmaxf(1e-28f, xx2 - xx1);  // EPS exactly as reference
                float hh = fmaxf(1e-28f, yy2 - yy1);
                float inter = ww * hh;
                float areaj = (b.z - b.x) * (b.w - b.y);
                // iou>0.5 <=> 3*inter > areai+areaj (denom>0); margin covers f32
                // rounding; also triggers on degenerate denom<=0 corners.
                hit |= ok && (3.0f * inter >= 0.9995f * (areai + areaj));
            }
        }
    }
    if (__ballot(hit) != 0ull && l == 0)
        __hip_atomic_store(flag, 1u, __ATOMIC_RELEASE, __HIP_MEMORY_SCOPE_AGENT);

    __syncthreads();
    if (t == 0) {
        __threadfence();
        __hip_atomic_store(&ready2[bi], MAGIC, __ATOMIC_RELEASE, __HIP_MEMORY_SCOPE_AGENT);
    }
    if (bi != 0) return;

    // ---- block 0: wait for all, run exact fallback iff any possible hit ----
    if (t < 64) {
        bool need0 = (t < NBLK), need1 = (t + 64 < NBLK);
        for (;;) {
            bool ok = (!need0 || __hip_atomic_load(&ready2[t], __ATOMIC_RELAXED,
                                     __HIP_MEMORY_SCOPE_AGENT) == MAGIC)
                   && (!need1 || __hip_atomic_load(&ready2[t + 64], __ATOMIC_RELAXED,
                                     __HIP_MEMORY_SCOPE_AGENT) == MAGIC);
            if (__ballot(ok) == ~0ull) break;
            __builtin_amdgcn_s_sleep(8);
        }
    }
    __syncthreads();
    __threadfence();
    if (t == 0)
        sh_flag = __hip_atomic_load(flag, __ATOMIC_RELAXED, __HIP_MEMORY_SCOPE_AGENT);
    __syncthreads();
    if (sh_flag != 1u) return;   // poison/zero/unset => clean fast path stands

    // ---- exact reference NMS (rank sort + sequential greedy), 256 threads ----
    for (int n = t; n < NBOX; n += 256)
        klds[n] = (((uint64_t)(~__float_as_uint(score[n]))) << 32) | (uint32_t)n;
    __syncthreads();
    for (int n = t; n < NBOX; n += 256) {
        uint64_t mk = klds[n];
        int r = 0;
        for (int j = 0; j < NBOX; j++) r += (klds[j] < mk) ? 1 : 0;
        sidx[r] = n;
        sscore[r] = score[n];
        sbox[r] = boff[n];
    }
    __syncthreads();
    for (int w2 = t; w2 < NBOX / 32; w2 += 256) {
        uint32_t v = 0;
        for (int b = 0; b < 32; b++) v |= (sscore[w2 * 32 + b] >= 0.01f) ? (1u << b) : 0u;
        keepb[w2] = v;
    }
    __syncthreads();
    for (int ii = 0; ii < NBOX; ii++) {
        bool kept = (keepb[ii >> 5] >> (ii & 31)) & 1u;   // uniform LDS broadcast
        if (kept) {
            float4 a = sbox[ii];
            float areaa = (a.z - a.x) * (a.w - a.y);
            for (int j = ii + 1 + t; j < NBOX; j += 256) {
                if ((keepb[j >> 5] >> (j & 31)) & 1u) {
                    float4 b = sbox[j];
                    float xx1 = fmaxf(a.x, b.x);
                    float yy1 = fmaxf(a.y, b.y);
                    float xx2 = fminf(a.z, b.z);
                    float yy2 = fminf(a.w, b.w);
                    float ww = fmaxf(1e-28f, xx2 - xx1);
                    float hh = fmaxf(1e-28f, yy2 - yy1);
                    float inter = ww * hh;
                    float areab = (b.z - b.x) * (b.w - b.y);
                    float iou = inter / (areaa + areab - inter);  // exact ref formula
                    if (iou > 0.5f) atomicAnd(&keepb[j >> 5], ~(1u << (j & 31)));
                }
            }
        }
        __syncthreads();
    }
    for (int r = t; r < NBOX; r += 256) {
        int orig = sidx[r];
        uint32_t kb = (keepb[r >> 5] >> (r & 31)) & 1u;
        out[38400 + orig] = (float)kb;
        out[25600 + orig] = kb ? sscore[r] : 0.0f;
    }
}

extern "C" void kernel_launch(void* const* d_in, const int* in_sizes, int n_in,
                              void* d_out, int out_size, void* d_ws, size_t ws_size,
                              hipStream_t stream) {
    const float* pred = (const float*)d_in[0];
    float* out = (float*)d_out;
    char* ws = (char*)d_ws;
    float4*   boff   = (float4*)(ws + 0);        // 6400 f4  (102400 B)
    float*    score  = (float*)(ws + 102400);    // 6400 f32
    float4*   blkbb  = (float4*)(ws + 128000);   // 100 f4 chunk bboxes
    uint64_t* validw = (uint64_t*)(ws + 129600); // 100 u64 valid ballots
    uint32_t* flag   = (uint32_t*)(ws + 130432); // 1 u32 (==1 only on hit)
    uint32_t* ready  = (uint32_t*)(ws + 130560); // 100 u32 magic flags
    uint32_t* ready2 = (uint32_t*)(ws + 131072); // 100 u32 magic flags
    int*      sidx   = (int*)(ws + 131584);      // slow path only
    float*    sscore = (float*)(ws + 157184);    // slow path only
    float4*   sbox   = (float4*)(ws + 182784);   // slow path only

    k_all<<<NBLK, 256, 0, stream>>>(pred, out, boff, score, blkbb, validw,
                                    flag, ready, ready2, sidx, sscore, sbox);
}

// Round 8
// 68.625 us; speedup vs baseline: 1.1083x; 1.1083x over previous
//
#include <hip/hip_runtime.h>
#include <stdint.h>

#define NBOX 6400
#define GRIDW 80
#define NC 20
#define NBLK 100       // NBOX / 64
#define NCH 9          // chunks tested per block: b..b+8 (covers all pairs with db<=8)
#define WMAX_PX 160.0f // raw-w bound: db>=9 pair requires some raw w > 160 px
#define MAGIC 0x13579BDFu

__device__ __forceinline__ float sigmoidf(float x) { return 1.0f / (1.0f + expf(-x)); }

// Full per-box decode, exact reference formulas (outputs must be bit-faithful).
__device__ __forceinline__ void decode_one(const float* __restrict__ p, int n,
        float4* box, float* score, int* cls, float* raww) {
    float conf = sigmoidf(p[0]);
    float c[NC];
    float m = -INFINITY;
    #pragma unroll
    for (int j = 0; j < NC; j++) { c[j] = p[1 + j]; m = fmaxf(m, c[j]); }
    float sum = 0.f;
    #pragma unroll
    for (int j = 0; j < NC; j++) { c[j] = expf(c[j] - m); sum += c[j]; }
    float best = -INFINITY; int bi = 0;
    #pragma unroll
    for (int j = 0; j < NC; j++) {
        float s = (c[j] / sum) * conf;        // softmax*conf, first-max argmax
        if (s > best) { best = s; bi = j; }
    }
    float gx = (float)(n / GRIDW);            // meshgrid 'ij': n = gx*80 + gy
    float gy = (float)(n % GRIDW);
    float cx = (gx + sigmoidf(p[21])) * 32.0f;
    float cy = (gy + sigmoidf(p[22])) * 32.0f;
    float w = expf(p[23]);
    float h = expf(p[24]);
    box->x = fminf(fmaxf((cx - w * 0.5f) / 2560.0f, 0.0f), 1.0f);
    box->y = fminf(fmaxf((cy - h * 0.5f) / 2560.0f, 0.0f), 1.0f);
    box->z = fminf(fmaxf((cx + w * 0.5f) / 2560.0f, 0.0f), 1.0f);
    box->w = fminf(fmaxf((cy + h * 0.5f) / 2560.0f, 0.0f), 1.0f);
    *score = best;
    *cls = bi;
    *raww = w;   // raw (pre-clip) width in px — reach bound for far pairs
}

// Single dispatch, 100 blocks x 256, NO grid barrier.
// Each block decodes chunks b..b+8 locally (LDS), writes outputs for own chunk
// (keep==valid, exact when no suppressing pair exists), tests every pair
// (i in chunk b, j in chunks b..b+8, j>i) with the conservative div-free
// IoU>0.5 test, and flags raw-w>160px boxes (only way a db>=9 pair can exist:
// chunk distance >=9 forces gx distance >=6 => center gap >160px). Invalid
// boxes are replaced by disjoint sentinels in the LDS screen copy.
// Block 99 polls per-block MAGIC flags (poison-safe) and runs the exact
// reference NMS iff any block reported a possible hit (never on this input).
__global__ __launch_bounds__(256) void k_all(const float* __restrict__ pred,
        float* __restrict__ out, float4* __restrict__ boff,
        float* __restrict__ score_g, uint32_t* __restrict__ hitw,
        uint32_t* __restrict__ ready, int* __restrict__ sidx,
        float* __restrict__ sscore, float4* __restrict__ sbox) {
    __shared__ float4 bl[NCH * 64];        // 9.2 KB: screen boxes (offset/sentinel)
    __shared__ uint64_t klds[NBOX];        // 51.2 KB, fallback only
    __shared__ uint32_t keepb[NBOX / 32];  // fallback only
    __shared__ uint32_t whit[4];
    __shared__ uint32_t sh_flag;
    int t = threadIdx.x;
    int w = t >> 6, l = t & 63;
    int b = blockIdx.x;
    int nreal = (NBLK - b) < NCH ? (NBLK - b) * 64 : NCH * 64;

    // ---- decode chunks b..b+8 into LDS (3 rounds of 256) ----
    bool bigbox = false;
    for (int m = t; m < NCH * 64; m += 256) {
        float4 ob;
        if (m < nreal) {
            int n = b * 64 + m;
            float4 bx; float s; int cls; float rw;
            decode_one(pred + (size_t)n * 25, n, &bx, &s, &cls, &rw);
            bool valid = s >= 0.01f;
            float off = 2.0f * (float)cls;            // class-offset trick
            float4 tob = make_float4(bx.x + off, bx.y + off, bx.z + off, bx.w + off);
            if (m < 64) {                             // own chunk: write outputs
                ((float4*)out)[n] = bx;               // output 0: boxes
                out[32000 + n] = (float)cls;          // output 2: class_idx
                out[25600 + n] = valid ? s : 0.0f;    // output 1: scores*keep
                out[38400 + n] = valid ? 1.0f : 0.0f; // output 3: keep
                score_g[n] = s;                       // publish for fallback
                boff[n] = tob;
                bigbox |= valid && (rw > WMAX_PX);    // far-pair reach bound
            }
            if (valid) ob = tob;
            else { float fx = -10000.0f - (float)m;   // disjoint sentinel, area .25
                   ob = make_float4(fx, 0.0f, fx + 0.5f, 0.5f); }
        } else {
            float fx = -10000.0f - (float)m;
            ob = make_float4(fx, 0.0f, fx + 0.5f, 0.5f);
        }
        bl[m] = ob;
    }
    __syncthreads();

    // ---- exact pair test: rows = own chunk, cols = chunks b..b+8 ----
    float4 rb = bl[l];                    // each wave covers all 64 rows
    float areai = (rb.z - rb.x) * (rb.w - rb.y);
    bool hit = bigbox;
    #pragma unroll
    for (int c = 0; c < NCH; c++) {
        #pragma unroll
        for (int k2 = 0; k2 < 16; k2++) {
            int s2 = w * 16 + k2;                 // wave-uniform column
            float4 bb = bl[c * 64 + s2];          // LDS broadcast read
            bool ok = !(c == 0 && s2 <= l);       // unordered pairs once (j>i)
            float xx1 = fmaxf(rb.x, bb.x);
            float yy1 = fmaxf(rb.y, bb.y);
            float xx2 = fminf(rb.z, bb.z);
            float yy2 = fminf(rb.w, bb.w);
            float ww = fmaxf(1e-28f, xx2 - xx1);  // EPS exactly as reference
            float hh = fmaxf(1e-28f, yy2 - yy1);
            float inter = ww * hh;
            float areaj = (bb.z - bb.x) * (bb.w - bb.y);
            // iou>0.5 <=> 3*inter > areai+areaj (denom>0); margin covers f32
            // rounding; also triggers on degenerate denom<=0 corners.
            hit |= ok && (3.0f * inter >= 0.9995f * (areai + areaj));
        }
    }
    whit[w] = (__ballot(hit) != 0ull) ? 1u : 0u;  // all lanes same value: benign
    __syncthreads();
    if (t == 0) {
        hitw[b] = whit[0] | whit[1] | whit[2] | whit[3];
        __threadfence();                          // publish hitw/score/boff
        __hip_atomic_store(&ready[b], MAGIC, __ATOMIC_RELEASE, __HIP_MEMORY_SCOPE_AGENT);
    }
    if (b != NBLK - 1) return;

    // ---- block 99: wait for all blocks, exact fallback iff any possible hit ----
    if (t < 64) {
        bool need0 = (t < NBLK), need1 = (t + 64 < NBLK);
        for (;;) {
            bool ok = (!need0 || __hip_atomic_load(&ready[t], __ATOMIC_RELAXED,
                                     __HIP_MEMORY_SCOPE_AGENT) == MAGIC)
                   && (!need1 || __hip_atomic_load(&ready[t + 64], __ATOMIC_RELAXED,
                                     __HIP_MEMORY_SCOPE_AGENT) == MAGIC);
            if (__ballot(ok) == ~0ull) break;
            __builtin_amdgcn_s_sleep(2);
        }
    }
    __syncthreads();
    __threadfence();   // acquire: hitw/score/boff from other blocks now visible
    if (t < 64) {
        uint32_t h = (t < NBLK ? hitw[t] : 0u) | (t + 64 < NBLK ? hitw[t + 64] : 0u);
        uint64_t anyb = __ballot(h == 1u);
        if (t == 0) sh_flag = (anyb != 0ull) ? 1u : 0u;
    }
    __syncthreads();
    if (sh_flag != 1u) return;   // clean: fast-path outputs stand

    // ---- exact reference NMS (rank sort + sequential greedy), 256 threads ----
    for (int n = t; n < NBOX; n += 256)
        klds[n] = (((uint64_t)(~__float_as_uint(score_g[n]))) << 32) | (uint32_t)n;
    __syncthreads();
    for (int n = t; n < NBOX; n += 256) {
        uint64_t mk = klds[n];
        int r = 0;
        for (int j = 0; j < NBOX; j++) r += (klds[j] < mk) ? 1 : 0;
        sidx[r] = n;
        sscore[r] = score_g[n];
        sbox[r] = boff[n];
    }
    __syncthreads();
    for (int w2 = t; w2 < NBOX / 32; w2 += 256) {
        uint32_t v = 0;
        for (int bb2 = 0; bb2 < 32; bb2++)
            v |= (sscore[w2 * 32 + bb2] >= 0.01f) ? (1u << bb2) : 0u;
        keepb[w2] = v;
    }
    __syncthreads();
    for (int ii = 0; ii < NBOX; ii++) {
        bool kept = (keepb[ii >> 5] >> (ii & 31)) & 1u;   // uniform LDS broadcast
        if (kept) {
            float4 a = sbox[ii];
            float areaa = (a.z - a.x) * (a.w - a.y);
            for (int j = ii + 1 + t; j < NBOX; j += 256) {
                if ((keepb[j >> 5] >> (j & 31)) & 1u) {
                    float4 bb = sbox[j];
                    float xx1 = fmaxf(a.x, bb.x);
                    float yy1 = fmaxf(a.y, bb.y);
                    float xx2 = fminf(a.z, bb.z);
                    float yy2 = fminf(a.w, bb.w);
                    float ww = fmaxf(1e-28f, xx2 - xx1);
                    float hh = fmaxf(1e-28f, yy2 - yy1);
                    float inter = ww * hh;
                    float areab = (bb.z - bb.x) * (bb.w - bb.y);
                    float iou = inter / (areaa + areab - inter);  // exact ref formula
                    if (iou > 0.5f) atomicAnd(&keepb[j >> 5], ~(1u << (j & 31)));
                }
            }
        }
        __syncthreads();
    }
    for (int r = t; r < NBOX; r += 256) {
        int orig = sidx[r];
        uint32_t kb = (keepb[r >> 5] >> (r & 31)) & 1u;
        out[38400 + orig] = (float)kb;
        out[25600 + orig] = kb ? sscore[r] : 0.0f;
    }
}

extern "C" void kernel_launch(void* const* d_in, const int* in_sizes, int n_in,
                              void* d_out, int out_size, void* d_ws, size_t ws_size,
                              hipStream_t stream) {
    const float* pred = (const float*)d_in[0];
    float* out = (float*)d_out;
    char* ws = (char*)d_ws;
    float4*   boff   = (float4*)(ws + 0);        // 6400 f4  (102400 B)
    float*    score  = (float*)(ws + 102400);    // 6400 f32
    uint32_t* hitw   = (uint32_t*)(ws + 128000); // 100 u32 per-block hit flags
    uint32_t* ready  = (uint32_t*)(ws + 128512); // 100 u32 MAGIC done flags
    int*      sidx   = (int*)(ws + 129024);      // slow path only
    float*    sscore = (float*)(ws + 154624);    // slow path only
    float4*   sbox   = (float4*)(ws + 180224);   // slow path only

    k_all<<<NBLK, 256, 0, stream>>>(pred, out, boff, score, hitw, ready,
                                    sidx, sscore, sbox);
}